// Round 9
// baseline (285.880 us; speedup 1.0000x reference)
//
#include <hip/hip_runtime.h>
#include <hip/hip_bf16.h>

#define B_ 8
#define C_ 512
#define L_ 2048
#define G_ 32

typedef __attribute__((ext_vector_type(8))) short bf16x8;
typedef __attribute__((ext_vector_type(4))) float f32x4;

__device__ __forceinline__ short f2b(float f) {
    union { float f; unsigned u; } c; c.f = f;
    unsigned r = (c.u + 0x7FFFu + ((c.u >> 16) & 1u)) >> 16;
    return (short)r;
}

__device__ __forceinline__ void load_lds16(const void* g, void* s) {
    __builtin_amdgcn_global_load_lds(
        (const __attribute__((address_space(1))) void*)g,
        (__attribute__((address_space(3))) void*)s, 16, 0, 0);
}

// counted vmcnt wait + scheduling fence (rule #18: sched_barrier after asm wait)
template<int N>
__device__ __forceinline__ void wait_vm() {
    if constexpr (N == 0)      asm volatile("s_waitcnt vmcnt(0)" ::: "memory");
    else if constexpr (N == 2) asm volatile("s_waitcnt vmcnt(2)" ::: "memory");
    else if constexpr (N == 6) asm volatile("s_waitcnt vmcnt(6)" ::: "memory");
    else                       asm volatile("s_waitcnt vmcnt(8)" ::: "memory");
    __builtin_amdgcn_sched_barrier(0);
}
__device__ __forceinline__ void wait_lgkm0() {
    asm volatile("s_waitcnt lgkmcnt(0)" ::: "memory");
    __builtin_amdgcn_sched_barrier(0);
}
__device__ __forceinline__ void sbar() {
    __builtin_amdgcn_sched_barrier(0);
    __builtin_amdgcn_s_barrier();
    __builtin_amdgcn_sched_barrier(0);
}

// -------- convert 4 fp32 512x512 weights to bf16, concatenated --------
__global__ __launch_bounds__(256) void cvt_w(
    const float* __restrict__ a, const float* __restrict__ b,
    const float* __restrict__ c, const float* __restrict__ d,
    short* __restrict__ o)
{
    const float* src = (blockIdx.y == 0) ? a : (blockIdx.y == 1) ? b
                     : (blockIdx.y == 2) ? c : d;
    short* dst = o + (size_t)blockIdx.y * (C_ * C_);
    int i = (blockIdx.x * 256 + threadIdx.x) * 4;
    float4 v = *(const float4*)(src + i);
    short4 r;
    r.x = f2b(v.x); r.y = f2b(v.y); r.z = f2b(v.z); r.w = f2b(v.w);
    *(short4*)(dst + i) = r;
}

// -------- GroupNorm + transpose: x[b,c,l] fp32 -> h_t[b,l,c] bf16 --------
// Pass 1 reads x coalesced (float4) AND stages the 16x2048 fp32 slab in LDS;
// pass 2 normalizes+transposes out of LDS (no scattered global re-read of x).
// Pass 2 handles cl-pairs -> packed 4B stores. Also zeroes rowsum (64/block).
__global__ __launch_bounds__(256) void groupnorm_tr(
    const float* __restrict__ x, const float* __restrict__ gamma,
    const float* __restrict__ beta, short* __restrict__ h_t,
    float* __restrict__ rsum)
{
    __shared__ float xb[16][2052];          // 131,328 B -> 1 block/CU
    __shared__ float rs[4], rss[4], stats[2], gam[16], bet[16];
    int bg = blockIdx.x;
    int b = bg >> 5, g = bg & 31;
    const float* xg = x + ((size_t)b * C_ + (size_t)g * 16) * L_;  // 32768 floats
    int t = threadIdx.x;
    if (t < 64) rsum[(size_t)bg * 64 + t] = 0.f;
    float s = 0.f, ss = 0.f;
    #pragma unroll 4
    for (int i = t; i < 8192; i += 256) {
        float4 v = ((const float4*)xg)[i];
        int cl = i >> 9, l4 = (i & 511) << 2;
        *(float4*)&xb[cl][l4] = v;
        s  += v.x + v.y + v.z + v.w;
        ss += v.x * v.x + v.y * v.y + v.z * v.z + v.w * v.w;
    }
    #pragma unroll
    for (int o = 32; o > 0; o >>= 1) { s += __shfl_down(s, o); ss += __shfl_down(ss, o); }
    int wave = t >> 6, lane = t & 63;
    if (lane == 0) { rs[wave] = s; rss[wave] = ss; }
    if (t < 16) { gam[t] = gamma[g * 16 + t]; bet[t] = beta[g * 16 + t]; }
    __syncthreads();
    if (t == 0) {
        float S = rs[0] + rs[1] + rs[2] + rs[3];
        float SS = rss[0] + rss[1] + rss[2] + rss[3];
        float mean = S * (1.f / 32768.f);
        float var = SS * (1.f / 32768.f) - mean * mean;
        stats[0] = mean; stats[1] = rsqrtf(var + 1e-5f);
    }
    __syncthreads();
    float mean = stats[0], rstd = stats[1];
    short* ho = h_t + (size_t)b * L_ * C_ + (size_t)g * 16;
    for (int i = t; i < 16384; i += 256) {
        int cp = (i & 7) * 2, l = i >> 3;
        float a0 = (xb[cp][l]     - mean) * rstd * gam[cp]     + bet[cp];
        float a1 = (xb[cp + 1][l] - mean) * rstd * gam[cp + 1] + bet[cp + 1];
        unsigned pk = (unsigned)(unsigned short)f2b(a0)
                    | ((unsigned)(unsigned short)f2b(a1) << 16);
        *(unsigned*)(ho + (size_t)l * C_ + cp) = pk;
    }
}

// ===================== 8-phase 256x256 GEMM (T3+T4+T5) ======================
// Used for qkproj only (measured best there, round 6/7).
#define MM(mh, nh, bfx)                                                        \
  do {                                                                         \
    _Pragma("unroll") for (int i_ = 0; i_ < 4; i_++)                           \
    _Pragma("unroll") for (int j_ = 0; j_ < 2; j_++)                           \
    _Pragma("unroll") for (int kk_ = 0; kk_ < 2; kk_++)                        \
      acc[(mh)*4 + i_][(nh)*2 + j_] = __builtin_amdgcn_mfma_f32_16x16x32_bf16( \
          af[i_][kk_], bfx[j_][kk_], acc[(mh)*4 + i_][(nh)*2 + j_], 0, 0, 0);  \
  } while (0)

template<int BIAS_MODE>
__global__ __launch_bounds__(512, 2) void gemm8(
    const short* __restrict__ A, const short* __restrict__ Bt,
    void* __restrict__ Co, const float* __restrict__ bias,
    const float* __restrict__ bias2, float* __restrict__ rowsum,
    int K, int lda, int ldb, int ldc,
    long sA, long sB, long sC, float alpha)
{
    __shared__ __align__(16) short As0[256 * 64];
    __shared__ __align__(16) short As1[256 * 64];
    __shared__ __align__(16) short Bs0[256 * 64];
    __shared__ __align__(16) short Bs1[256 * 64];

    int nbx = gridDim.x, nby = gridDim.y, nbz = gridDim.z;
    int lin = blockIdx.x + nbx * (blockIdx.y + nby * blockIdx.z);
    int total = nbx * nby * nbz;
    int bx, by, bz;
    if ((total & 7) == 0) {
        int chunk = total >> 3;
        int logical = (lin & 7) * chunk + (lin >> 3);
        bx = logical % nbx; int t2 = logical / nbx; by = t2 % nby; bz = t2 / nby;
    } else { bx = blockIdx.x; by = blockIdx.y; bz = blockIdx.z; }

    int m0 = by * 256, n0 = bx * 256;
    int t = threadIdx.x, lane = t & 63;
    int wave = t >> 6;
    int wm = wave >> 2, wn = wave & 3;        // 2 M-waves x 4 N-waves
    int fr = lane & 15, fq = lane >> 4;
    int ch0 = (fq ^ (fr & 7)) << 3;
    int ch1 = ((4 | fq) ^ (fr & 7)) << 3;
    int rs_ = t >> 3, cs_ = t & 7;
    int gcol = ((cs_ ^ (rs_ & 7)) << 3);

    const short* gA = A + (size_t)bz * sA + (size_t)(m0 + rs_) * lda + gcol;
    const short* gB = Bt + (size_t)bz * sB + (size_t)(n0 + rs_) * ldb + gcol;

    f32x4 acc[8][4] = {};
    bf16x8 af[4][2], bf0[2][2], bf1[2][2];

    auto stgA = [&](short* dst, int tile, int h) {
        const short* s = gA + (size_t)(h * 128) * lda + tile * 64;
        load_lds16(s, dst + h * 8192 + t * 8);
        load_lds16(s + (size_t)64 * lda, dst + h * 8192 + 4096 + t * 8);
    };
    auto stgB = [&](short* dst, int tile, int h) {
        const short* s = gB + (size_t)(h * 128) * ldb + tile * 64;
        load_lds16(s, dst + h * 8192 + t * 8);
        load_lds16(s + (size_t)64 * ldb, dst + h * 8192 + 4096 + t * 8);
    };
    auto rdA = [&](const short* S, int mh) {
        #pragma unroll
        for (int i = 0; i < 4; i++) {
            int R = wm * 128 + (mh * 4 + i) * 16 + fr;
            af[i][0] = *(const bf16x8*)(S + R * 64 + ch0);
            af[i][1] = *(const bf16x8*)(S + R * 64 + ch1);
        }
    };
    auto rdB = [&](const short* S, int nh, bf16x8 (&bf)[2][2]) {
        #pragma unroll
        for (int j = 0; j < 2; j++) {
            int R = wn * 64 + (nh * 2 + j) * 16 + fr;
            bf[j][0] = *(const bf16x8*)(S + R * 64 + ch0);
            bf[j][1] = *(const bf16x8*)(S + R * 64 + ch1);
        }
    };

    int nk = K >> 6;

    auto TILE = [&](short* cA, short* cB, short* nA, short* nB, int tt) {
        rdA(cA, 0); rdB(cB, 0, bf0);
        if (tt + 1 < nk) stgA(nA, tt + 1, 1);
        sbar(); wait_lgkm0();
        __builtin_amdgcn_s_setprio(1); MM(0, 0, bf0); __builtin_amdgcn_s_setprio(0);
        sbar();
        rdB(cB, 1, bf1);
        if (tt + 1 < nk) stgB(nB, tt + 1, 0);
        sbar(); wait_lgkm0();
        __builtin_amdgcn_s_setprio(1); MM(0, 1, bf1); __builtin_amdgcn_s_setprio(0);
        sbar();
        rdA(cA, 1);
        if (tt + 1 < nk) stgB(nB, tt + 1, 1);
        sbar(); wait_lgkm0();
        __builtin_amdgcn_s_setprio(1); MM(1, 0, bf0); __builtin_amdgcn_s_setprio(0);
        sbar();
        if (tt + 2 < nk) stgA(cA, tt + 2, 0);
        __builtin_amdgcn_s_setprio(1); MM(1, 1, bf1); __builtin_amdgcn_s_setprio(0);
        if (tt + 2 < nk) wait_vm<2>(); else wait_vm<0>();
        sbar();
    };

    stgA(As0, 0, 0); stgA(As0, 0, 1); stgB(Bs0, 0, 0); stgB(Bs0, 0, 1);
    if (nk > 1) stgA(As1, 1, 0);
    wait_vm<2>();
    sbar();

    for (int tt = 0; tt < nk; tt += 2) {
        TILE(As0, Bs0, As1, Bs1, tt);
        TILE(As1, Bs1, As0, Bs0, tt + 1);
    }

    size_t cb = (size_t)bz * sC;
    int crow = fq * 4;
    #pragma unroll
    for (int mi = 0; mi < 8; mi++) {
        #pragma unroll
        for (int nj = 0; nj < 4; nj++) {
            int n = n0 + wn * 64 + nj * 16 + fr;
            float bn = 0.f;
            if (BIAS_MODE == 3) bn = (n < 512) ? bias[n] : bias2[n - 512];
            #pragma unroll
            for (int r = 0; r < 4; r++) {
                int m = m0 + wm * 128 + mi * 16 + crow + r;
                float v = acc[mi][nj][r] * alpha;
                if (BIAS_MODE == 3) v += bn;
                ((short*)Co)[cb + (size_t)m * ldc + n] = f2b(v);
            }
        }
    }
}

// -------- bt-GEMM: BM x 128 tile, BK=64, XOR-swizzled LDS ----------------
// PIPE=0: single-buffer 2-barrier K-loop (best for BM=256 M=2048-class shapes:
//         48 KiB LDS -> 3 blocks/CU, TLP covers latency; QK measured 62.5 us).
// PIPE=1: dbuf + counted vmcnt (best for the BM=128 vproj/outproj kernels).
// EXPSUM epilogue uses exp2 (alpha pre-scaled by log2(e) at call site).
template<int BM, int PIPE, int BIAS_MODE, bool RESID, bool OUTF32, bool EXPSUM, bool ROWDIV>
__global__ __launch_bounds__(BM * 2) void gemm_bt(
    const short* __restrict__ A, const short* __restrict__ Bt,
    void* __restrict__ Co, const float* __restrict__ bias,
    const float* __restrict__ bias2, const float* __restrict__ resid,
    float* __restrict__ rowsum,
    int N, int K, int lda, int ldb, int ldc,
    long sA, long sB, long sC, float alpha)
{
    constexpr int T = BM * 2;
    constexpr int RPP = T / 8;
    constexpr int LPS = BM / RPP + 128 / RPP;
    constexpr int NBUF = (PIPE == 1) ? 2 : 1;
    __shared__ __align__(16) short As[NBUF][BM * 64];
    __shared__ __align__(16) short Bs[NBUF][128 * 64];

    int nbx = gridDim.x, nby = gridDim.y, nbz = gridDim.z;
    int lin = blockIdx.x + nbx * (blockIdx.y + nby * blockIdx.z);
    int total = nbx * nby * nbz;
    int bx, by, bz;
    if ((total & 7) == 0) {
        int chunk = total >> 3;
        int logical = (lin & 7) * chunk + (lin >> 3);
        bx = logical % nbx; int t2 = logical / nbx; by = t2 % nby; bz = t2 / nby;
    } else { bx = blockIdx.x; by = blockIdx.y; bz = blockIdx.z; }

    const short* Ab = A + (size_t)bz * sA;
    const short* Bb = Bt + (size_t)bz * sB;
    int m0 = by * BM, n0 = bx * 128;
    int t = threadIdx.x, lane = t & 63;
    int wave = t >> 6;
    int wm = wave >> 1, wn = wave & 1;

    f32x4 acc[4][4] = {};

    int rs_ = t >> 3, cs_ = t & 7;
    int gcol = ((cs_ ^ (rs_ & 7)) << 3);
    const short* gA = Ab + (size_t)(m0 + rs_) * lda + gcol;
    const short* gB = Bb + (size_t)(n0 + rs_) * ldb + gcol;
    int fr = lane & 15, fq = lane >> 4;
    int ch0 = (fq ^ (fr & 7)) << 3;
    int ch1 = ((4 | fq) ^ (fr & 7)) << 3;

    auto stage = [&](short* Asb, short* Bsb) {
        #pragma unroll
        for (int i = 0; i < BM / RPP; i++)
            load_lds16(gA + (size_t)(RPP * i) * lda, Asb + i * (RPP * 64) + t * 8);
        #pragma unroll
        for (int i = 0; i < 128 / RPP; i++)
            load_lds16(gB + (size_t)(RPP * i) * ldb, Bsb + i * (RPP * 64) + t * 8);
        gA += 64; gB += 64;
    };
    auto compute = [&](const short* Asb, const short* Bsb) {
        #pragma unroll
        for (int kk = 0; kk < 2; kk++) {
            int ch = kk ? ch1 : ch0;
            bf16x8 af[4], bfr[4];
            #pragma unroll
            for (int i = 0; i < 4; i++)
                af[i] = *(const bf16x8*)(Asb + (wm * 64 + i * 16 + fr) * 64 + ch);
            #pragma unroll
            for (int j = 0; j < 4; j++)
                bfr[j] = *(const bf16x8*)(Bsb + (wn * 64 + j * 16 + fr) * 64 + ch);
            #pragma unroll
            for (int mt = 0; mt < 4; mt++)
                #pragma unroll
                for (int nt = 0; nt < 4; nt++)
                    acc[mt][nt] = __builtin_amdgcn_mfma_f32_16x16x32_bf16(
                        af[mt], bfr[nt], acc[mt][nt], 0, 0, 0);
        }
    };

    if constexpr (PIPE == 0) {
        for (int k0 = 0; k0 < K; k0 += 64) {
            __syncthreads();
            stage(As[0], Bs[0]);
            __syncthreads();
            compute(As[0], Bs[0]);
        }
    } else {
        int nk = K >> 6;
        stage(As[0], Bs[0]);
        stage(As[1], Bs[1]);
        wait_vm<LPS>();
        sbar();
        for (int kt = 0; kt < nk; kt += 2) {
            compute(As[0], Bs[0]);
            sbar();
            if (kt + 2 < nk) { stage(As[0], Bs[0]); wait_vm<LPS>(); }
            else               wait_vm<0>();
            sbar();
            compute(As[1], Bs[1]);
            sbar();
            if (kt + 3 < nk) { stage(As[1], Bs[1]); wait_vm<LPS>(); }
            else               wait_vm<0>();
            sbar();
        }
    }

    size_t cb = (size_t)bz * sC;
    int crow = (lane >> 4) * 4;
    int wrow = wm * 64;
    float psum[4][4];
    float inv[4][4];
    if (EXPSUM) {
        #pragma unroll
        for (int mt = 0; mt < 4; mt++)
            #pragma unroll
            for (int r = 0; r < 4; r++) psum[mt][r] = 0.f;
    }
    if (ROWDIV) {
        #pragma unroll
        for (int mt = 0; mt < 4; mt++)
            #pragma unroll
            for (int r = 0; r < 4; r++) {
                int m = m0 + wrow + mt * 16 + crow + r;
                inv[mt][r] = 1.f / rowsum[(size_t)bz * L_ + m];
            }
    }
    #pragma unroll
    for (int mt = 0; mt < 4; mt++) {
        #pragma unroll
        for (int nt = 0; nt < 4; nt++) {
            int n = n0 + wn * 64 + nt * 16 + fr;
            float bn = 0.f;
            if (BIAS_MODE == 3) bn = (n < 512) ? bias[n] : bias2[n - 512];
            #pragma unroll
            for (int r = 0; r < 4; r++) {
                int m = m0 + wrow + mt * 16 + crow + r;
                float v = acc[mt][nt][r] * alpha;
                if (EXPSUM) { v = exp2f(v); psum[mt][r] += v; }
                if (ROWDIV) v *= inv[mt][r];
                if (BIAS_MODE == 3) v += bn;
                if (BIAS_MODE == 2) v += bias[m];
                size_t idx = cb + (size_t)m * ldc + n;
                if (RESID) v += resid[idx];
                if (OUTF32) ((float*)Co)[idx] = v;
                else        ((short*)Co)[idx] = f2b(v);
            }
        }
    }
    if (EXPSUM) {
        #pragma unroll
        for (int mt = 0; mt < 4; mt++)
            #pragma unroll
            for (int r = 0; r < 4; r++) {
                float s = psum[mt][r];
                s += __shfl_xor(s, 1); s += __shfl_xor(s, 2);
                s += __shfl_xor(s, 4); s += __shfl_xor(s, 8);
                if ((lane & 15) == 0) {
                    int m = m0 + wrow + mt * 16 + crow + r;
                    atomicAdd(rowsum + (size_t)bz * L_ + m, s);
                }
            }
    }
}

extern "C" void kernel_launch(void* const* d_in, const int* in_sizes, int n_in,
                              void* d_out, int out_size, void* d_ws, size_t ws_size,
                              hipStream_t stream)
{
    const float* x     = (const float*)d_in[0];
    const float* gamma = (const float*)d_in[1];
    const float* beta  = (const float*)d_in[2];
    const float* Wq    = (const float*)d_in[3];
    const float* bq    = (const float*)d_in[4];
    const float* Wk    = (const float*)d_in[5];
    const float* bk    = (const float*)d_in[6];
    const float* Wv    = (const float*)d_in[7];
    const float* bv    = (const float*)d_in[8];
    const float* Wo    = (const float*)d_in[9];
    const float* bo    = (const float*)d_in[10];
    float* out = (float*)d_out;

    const size_t MiB = 1024 * 1024;
    const size_t CC = (size_t)C_ * C_;
    const size_t LC = (size_t)L_ * C_;
    const size_t LL = (size_t)L_ * L_;
    const size_t wbytes = 4 * CC * sizeof(short);

    const size_t perb = 16 * MiB + L_ * sizeof(float);
    int nb = 1;
    for (int c = 8; c >= 1; c >>= 1)
        if (ws_size >= wbytes + (size_t)c * perb) { nb = c; break; }

    short* wq_b = (short*)d_ws;       // rows 0-511 Wq, 512-1023 Wk (contiguous)
    short* wv_b = wq_b + 2 * CC;
    short* wo_b = wv_b + CC;
    short* h_t  = wo_b + CC;
    short* qk_t = h_t + (size_t)nb * LC;
    short* v_   = qk_t + (size_t)nb * 2 * LC;
    short* S    = v_  + (size_t)nb * LC;
    float* rsum = (float*)(S + (size_t)nb * LL);
    short* a_t  = h_t;                              // h_t dead after vproj

    const long sLC = (long)LC;
    const long sLL = (long)LL;
    // 1/sqrt(512) * log2(e): QK epilogue uses exp2
    const float alpha2 = 0.04419417382415922f * 1.4426950408889634f;

    cvt_w<<<dim3(C_ * C_ / 1024, 4), 256, 0, stream>>>(Wq, Wk, Wv, Wo, wq_b);

    for (int b0 = 0; b0 < B_; b0 += nb) {
        const float* xb = x + (size_t)b0 * LC;
        float* outb = out + (size_t)b0 * LC;

        groupnorm_tr<<<dim3(nb * G_), 256, 0, stream>>>(xb, gamma, beta, h_t, rsum);

        // qk_t[l, 0..1023] = h_t[l,:]·[Wq;Wk]^T + [bq;bk]   (8-phase 256²)
        gemm8<3><<<dim3(4, 8, nb), 512, 0, stream>>>(
            h_t, wq_b, qk_t, bq, bk, nullptr,
            512, 512, 512, 1024, sLC, 0, 2 * sLC, 1.f);
        // v[c,l] = Wv·h^T + bv   (BM=128 PIPE=1, measured best)
        gemm_bt<128, 1, 2, false, false, false, false><<<dim3(16, 4, nb), 256, 0, stream>>>(
            wv_b, h_t, v_, bv, nullptr, nullptr, nullptr,
            2048, 512, 512, 512, 2048, 0, sLC, sLC, 1.f);
        // S = exp2(a2 * q.k); rowsum partials   (BM=256 PIPE=0, measured best)
        gemm_bt<256, 0, 0, false, false, true, false><<<dim3(16, 8, nb), 512, 0, stream>>>(
            qk_t, qk_t + 512, S, nullptr, nullptr, nullptr, rsum,
            2048, 512, 1024, 1024, 2048, 2 * sLC, 2 * sLC, sLL, alpha2);
        // a_t[i,c] = (sum_j S[i,j] v[c,j]) / rowsum[i]   (NEW: BM=256 PIPE=0)
        gemm_bt<256, 0, 0, false, false, false, true><<<dim3(4, 8, nb), 512, 0, stream>>>(
            S, v_, a_t, nullptr, nullptr, nullptr, rsum,
            512, 2048, 2048, 2048, 512, sLL, sLC, sLC, 1.f);
        // out[c,l] = x[c,l] + bo[c] + Wo·a^T   (fp32 out; BM=128 PIPE=1)
        gemm_bt<128, 1, 2, true, true, false, false><<<dim3(16, 4, nb), 256, 0, stream>>>(
            wo_b, a_t, outb, bo, nullptr, xb, nullptr,
            2048, 512, 512, 512, 2048, 0, sLC, sLC, 1.f);
    }
}

// Round 10
// 270.270 us; speedup vs baseline: 1.0578x; 1.0578x over previous
//
#include <hip/hip_runtime.h>
#include <hip/hip_bf16.h>

#define B_ 8
#define C_ 512
#define L_ 2048
#define G_ 32

typedef __attribute__((ext_vector_type(8))) short bf16x8;
typedef __attribute__((ext_vector_type(4))) float f32x4;

__device__ __forceinline__ short f2b(float f) {
    union { float f; unsigned u; } c; c.f = f;
    unsigned r = (c.u + 0x7FFFu + ((c.u >> 16) & 1u)) >> 16;
    return (short)r;
}

__device__ __forceinline__ void load_lds16(const void* g, void* s) {
    __builtin_amdgcn_global_load_lds(
        (const __attribute__((address_space(1))) void*)g,
        (__attribute__((address_space(3))) void*)s, 16, 0, 0);
}

// counted vmcnt wait + scheduling fence (rule #18: sched_barrier after asm wait)
template<int N>
__device__ __forceinline__ void wait_vm() {
    if constexpr (N == 0)      asm volatile("s_waitcnt vmcnt(0)" ::: "memory");
    else if constexpr (N == 2) asm volatile("s_waitcnt vmcnt(2)" ::: "memory");
    else if constexpr (N == 6) asm volatile("s_waitcnt vmcnt(6)" ::: "memory");
    else                       asm volatile("s_waitcnt vmcnt(8)" ::: "memory");
    __builtin_amdgcn_sched_barrier(0);
}
__device__ __forceinline__ void wait_lgkm0() {
    asm volatile("s_waitcnt lgkmcnt(0)" ::: "memory");
    __builtin_amdgcn_sched_barrier(0);
}
__device__ __forceinline__ void sbar() {
    __builtin_amdgcn_sched_barrier(0);
    __builtin_amdgcn_s_barrier();
    __builtin_amdgcn_sched_barrier(0);
}

// -------- convert 4 fp32 512x512 weights to bf16, concatenated --------
__global__ __launch_bounds__(256) void cvt_w(
    const float* __restrict__ a, const float* __restrict__ b,
    const float* __restrict__ c, const float* __restrict__ d,
    short* __restrict__ o)
{
    const float* src = (blockIdx.y == 0) ? a : (blockIdx.y == 1) ? b
                     : (blockIdx.y == 2) ? c : d;
    short* dst = o + (size_t)blockIdx.y * (C_ * C_);
    int i = (blockIdx.x * 256 + threadIdx.x) * 4;
    float4 v = *(const float4*)(src + i);
    short4 r;
    r.x = f2b(v.x); r.y = f2b(v.y); r.z = f2b(v.z); r.w = f2b(v.w);
    *(short4*)(dst + i) = r;
}

// -------- GroupNorm + transpose: x[b,c,l] fp32 -> h_t[b,l,c] bf16 --------
// Pass 1 reads x coalesced (float4) AND stages the 16x2048 fp32 slab in LDS;
// pass 2 normalizes+transposes out of LDS (no scattered global re-read of x).
// Pass 2 handles cl-pairs -> packed 4B stores. Also zeroes rowsum (64/block).
__global__ __launch_bounds__(256) void groupnorm_tr(
    const float* __restrict__ x, const float* __restrict__ gamma,
    const float* __restrict__ beta, short* __restrict__ h_t,
    float* __restrict__ rsum)
{
    __shared__ float xb[16][2052];          // 131,328 B -> 1 block/CU
    __shared__ float rs[4], rss[4], stats[2], gam[16], bet[16];
    int bg = blockIdx.x;
    int b = bg >> 5, g = bg & 31;
    const float* xg = x + ((size_t)b * C_ + (size_t)g * 16) * L_;  // 32768 floats
    int t = threadIdx.x;
    if (t < 64) rsum[(size_t)bg * 64 + t] = 0.f;
    float s = 0.f, ss = 0.f;
    #pragma unroll 4
    for (int i = t; i < 8192; i += 256) {
        float4 v = ((const float4*)xg)[i];
        int cl = i >> 9, l4 = (i & 511) << 2;
        *(float4*)&xb[cl][l4] = v;
        s  += v.x + v.y + v.z + v.w;
        ss += v.x * v.x + v.y * v.y + v.z * v.z + v.w * v.w;
    }
    #pragma unroll
    for (int o = 32; o > 0; o >>= 1) { s += __shfl_down(s, o); ss += __shfl_down(ss, o); }
    int wave = t >> 6, lane = t & 63;
    if (lane == 0) { rs[wave] = s; rss[wave] = ss; }
    if (t < 16) { gam[t] = gamma[g * 16 + t]; bet[t] = beta[g * 16 + t]; }
    __syncthreads();
    if (t == 0) {
        float S = rs[0] + rs[1] + rs[2] + rs[3];
        float SS = rss[0] + rss[1] + rss[2] + rss[3];
        float mean = S * (1.f / 32768.f);
        float var = SS * (1.f / 32768.f) - mean * mean;
        stats[0] = mean; stats[1] = rsqrtf(var + 1e-5f);
    }
    __syncthreads();
    float mean = stats[0], rstd = stats[1];
    short* ho = h_t + (size_t)b * L_ * C_ + (size_t)g * 16;
    for (int i = t; i < 16384; i += 256) {
        int cp = (i & 7) * 2, l = i >> 3;
        float a0 = (xb[cp][l]     - mean) * rstd * gam[cp]     + bet[cp];
        float a1 = (xb[cp + 1][l] - mean) * rstd * gam[cp + 1] + bet[cp + 1];
        unsigned pk = (unsigned)(unsigned short)f2b(a0)
                    | ((unsigned)(unsigned short)f2b(a1) << 16);
        *(unsigned*)(ho + (size_t)l * C_ + cp) = pk;
    }
}

// ===================== 8-phase 256x256 GEMM (T3+T4+T5) ======================
// Used for qkproj only (measured best there, rounds 6/7).
#define MM(mh, nh, bfx)                                                        \
  do {                                                                         \
    _Pragma("unroll") for (int i_ = 0; i_ < 4; i_++)                           \
    _Pragma("unroll") for (int j_ = 0; j_ < 2; j_++)                           \
    _Pragma("unroll") for (int kk_ = 0; kk_ < 2; kk_++)                        \
      acc[(mh)*4 + i_][(nh)*2 + j_] = __builtin_amdgcn_mfma_f32_16x16x32_bf16( \
          af[i_][kk_], bfx[j_][kk_], acc[(mh)*4 + i_][(nh)*2 + j_], 0, 0, 0);  \
  } while (0)

template<int BIAS_MODE>
__global__ __launch_bounds__(512, 2) void gemm8(
    const short* __restrict__ A, const short* __restrict__ Bt,
    void* __restrict__ Co, const float* __restrict__ bias,
    const float* __restrict__ bias2, float* __restrict__ rowsum,
    int K, int lda, int ldb, int ldc,
    long sA, long sB, long sC, float alpha)
{
    __shared__ __align__(16) short As0[256 * 64];
    __shared__ __align__(16) short As1[256 * 64];
    __shared__ __align__(16) short Bs0[256 * 64];
    __shared__ __align__(16) short Bs1[256 * 64];

    int nbx = gridDim.x, nby = gridDim.y, nbz = gridDim.z;
    int lin = blockIdx.x + nbx * (blockIdx.y + nby * blockIdx.z);
    int total = nbx * nby * nbz;
    int bx, by, bz;
    if ((total & 7) == 0) {
        int chunk = total >> 3;
        int logical = (lin & 7) * chunk + (lin >> 3);
        bx = logical % nbx; int t2 = logical / nbx; by = t2 % nby; bz = t2 / nby;
    } else { bx = blockIdx.x; by = blockIdx.y; bz = blockIdx.z; }

    int m0 = by * 256, n0 = bx * 256;
    int t = threadIdx.x, lane = t & 63;
    int wave = t >> 6;
    int wm = wave >> 2, wn = wave & 3;        // 2 M-waves x 4 N-waves
    int fr = lane & 15, fq = lane >> 4;
    int ch0 = (fq ^ (fr & 7)) << 3;
    int ch1 = ((4 | fq) ^ (fr & 7)) << 3;
    int rs_ = t >> 3, cs_ = t & 7;
    int gcol = ((cs_ ^ (rs_ & 7)) << 3);

    const short* gA = A + (size_t)bz * sA + (size_t)(m0 + rs_) * lda + gcol;
    const short* gB = Bt + (size_t)bz * sB + (size_t)(n0 + rs_) * ldb + gcol;

    f32x4 acc[8][4] = {};
    bf16x8 af[4][2], bf0[2][2], bf1[2][2];

    auto stgA = [&](short* dst, int tile, int h) {
        const short* s = gA + (size_t)(h * 128) * lda + tile * 64;
        load_lds16(s, dst + h * 8192 + t * 8);
        load_lds16(s + (size_t)64 * lda, dst + h * 8192 + 4096 + t * 8);
    };
    auto stgB = [&](short* dst, int tile, int h) {
        const short* s = gB + (size_t)(h * 128) * ldb + tile * 64;
        load_lds16(s, dst + h * 8192 + t * 8);
        load_lds16(s + (size_t)64 * ldb, dst + h * 8192 + 4096 + t * 8);
    };
    auto rdA = [&](const short* S, int mh) {
        #pragma unroll
        for (int i = 0; i < 4; i++) {
            int R = wm * 128 + (mh * 4 + i) * 16 + fr;
            af[i][0] = *(const bf16x8*)(S + R * 64 + ch0);
            af[i][1] = *(const bf16x8*)(S + R * 64 + ch1);
        }
    };
    auto rdB = [&](const short* S, int nh, bf16x8 (&bf)[2][2]) {
        #pragma unroll
        for (int j = 0; j < 2; j++) {
            int R = wn * 64 + (nh * 2 + j) * 16 + fr;
            bf[j][0] = *(const bf16x8*)(S + R * 64 + ch0);
            bf[j][1] = *(const bf16x8*)(S + R * 64 + ch1);
        }
    };

    int nk = K >> 6;

    auto TILE = [&](short* cA, short* cB, short* nA, short* nB, int tt) {
        rdA(cA, 0); rdB(cB, 0, bf0);
        if (tt + 1 < nk) stgA(nA, tt + 1, 1);
        sbar(); wait_lgkm0();
        __builtin_amdgcn_s_setprio(1); MM(0, 0, bf0); __builtin_amdgcn_s_setprio(0);
        sbar();
        rdB(cB, 1, bf1);
        if (tt + 1 < nk) stgB(nB, tt + 1, 0);
        sbar(); wait_lgkm0();
        __builtin_amdgcn_s_setprio(1); MM(0, 1, bf1); __builtin_amdgcn_s_setprio(0);
        sbar();
        rdA(cA, 1);
        if (tt + 1 < nk) stgB(nB, tt + 1, 1);
        sbar(); wait_lgkm0();
        __builtin_amdgcn_s_setprio(1); MM(1, 0, bf0); __builtin_amdgcn_s_setprio(0);
        sbar();
        if (tt + 2 < nk) stgA(cA, tt + 2, 0);
        __builtin_amdgcn_s_setprio(1); MM(1, 1, bf1); __builtin_amdgcn_s_setprio(0);
        if (tt + 2 < nk) wait_vm<2>(); else wait_vm<0>();
        sbar();
    };

    stgA(As0, 0, 0); stgA(As0, 0, 1); stgB(Bs0, 0, 0); stgB(Bs0, 0, 1);
    if (nk > 1) stgA(As1, 1, 0);
    wait_vm<2>();
    sbar();

    for (int tt = 0; tt < nk; tt += 2) {
        TILE(As0, Bs0, As1, Bs1, tt);
        TILE(As1, Bs1, As0, Bs0, tt + 1);
    }

    size_t cb = (size_t)bz * sC;
    int crow = fq * 4;
    #pragma unroll
    for (int mi = 0; mi < 8; mi++) {
        #pragma unroll
        for (int nj = 0; nj < 4; nj++) {
            int n = n0 + wn * 64 + nj * 16 + fr;
            float bn = 0.f;
            if (BIAS_MODE == 3) bn = (n < 512) ? bias[n] : bias2[n - 512];
            #pragma unroll
            for (int r = 0; r < 4; r++) {
                int m = m0 + wm * 128 + mi * 16 + crow + r;
                float v = acc[mi][nj][r] * alpha;
                if (BIAS_MODE == 3) v += bn;
                ((short*)Co)[cb + (size_t)m * ldc + n] = f2b(v);
            }
        }
    }
}

// -------- bt-GEMM: BM x 128 tile, BK=64, XOR-swizzled LDS ----------------
// PIPE=0: single-buffer 2-barrier K-loop (best for BM=256 QK: 62.5 us,
//         48 KiB LDS -> 3 blocks/CU, TLP covers latency).
// PIPE=1: dbuf + counted vmcnt (best for BM=128 vproj/PV/outproj).
// EXPSUM epilogue: __expf (round-9 showed exp2f library call costs +2.4 us).
template<int BM, int PIPE, int BIAS_MODE, bool RESID, bool OUTF32, bool EXPSUM, bool ROWDIV>
__global__ __launch_bounds__(BM * 2) void gemm_bt(
    const short* __restrict__ A, const short* __restrict__ Bt,
    void* __restrict__ Co, const float* __restrict__ bias,
    const float* __restrict__ bias2, const float* __restrict__ resid,
    float* __restrict__ rowsum,
    int N, int K, int lda, int ldb, int ldc,
    long sA, long sB, long sC, float alpha)
{
    constexpr int T = BM * 2;
    constexpr int RPP = T / 8;
    constexpr int LPS = BM / RPP + 128 / RPP;
    constexpr int NBUF = (PIPE == 1) ? 2 : 1;
    __shared__ __align__(16) short As[NBUF][BM * 64];
    __shared__ __align__(16) short Bs[NBUF][128 * 64];

    int nbx = gridDim.x, nby = gridDim.y, nbz = gridDim.z;
    int lin = blockIdx.x + nbx * (blockIdx.y + nby * blockIdx.z);
    int total = nbx * nby * nbz;
    int bx, by, bz;
    if ((total & 7) == 0) {
        int chunk = total >> 3;
        int logical = (lin & 7) * chunk + (lin >> 3);
        bx = logical % nbx; int t2 = logical / nbx; by = t2 % nby; bz = t2 / nby;
    } else { bx = blockIdx.x; by = blockIdx.y; bz = blockIdx.z; }

    const short* Ab = A + (size_t)bz * sA;
    const short* Bb = Bt + (size_t)bz * sB;
    int m0 = by * BM, n0 = bx * 128;
    int t = threadIdx.x, lane = t & 63;
    int wave = t >> 6;
    int wm = wave >> 1, wn = wave & 1;

    f32x4 acc[4][4] = {};

    int rs_ = t >> 3, cs_ = t & 7;
    int gcol = ((cs_ ^ (rs_ & 7)) << 3);
    const short* gA = Ab + (size_t)(m0 + rs_) * lda + gcol;
    const short* gB = Bb + (size_t)(n0 + rs_) * ldb + gcol;
    int fr = lane & 15, fq = lane >> 4;
    int ch0 = (fq ^ (fr & 7)) << 3;
    int ch1 = ((4 | fq) ^ (fr & 7)) << 3;

    auto stage = [&](short* Asb, short* Bsb) {
        #pragma unroll
        for (int i = 0; i < BM / RPP; i++)
            load_lds16(gA + (size_t)(RPP * i) * lda, Asb + i * (RPP * 64) + t * 8);
        #pragma unroll
        for (int i = 0; i < 128 / RPP; i++)
            load_lds16(gB + (size_t)(RPP * i) * ldb, Bsb + i * (RPP * 64) + t * 8);
        gA += 64; gB += 64;
    };
    auto compute = [&](const short* Asb, const short* Bsb) {
        #pragma unroll
        for (int kk = 0; kk < 2; kk++) {
            int ch = kk ? ch1 : ch0;
            bf16x8 af[4], bfr[4];
            #pragma unroll
            for (int i = 0; i < 4; i++)
                af[i] = *(const bf16x8*)(Asb + (wm * 64 + i * 16 + fr) * 64 + ch);
            #pragma unroll
            for (int j = 0; j < 4; j++)
                bfr[j] = *(const bf16x8*)(Bsb + (wn * 64 + j * 16 + fr) * 64 + ch);
            #pragma unroll
            for (int mt = 0; mt < 4; mt++)
                #pragma unroll
                for (int nt = 0; nt < 4; nt++)
                    acc[mt][nt] = __builtin_amdgcn_mfma_f32_16x16x32_bf16(
                        af[mt], bfr[nt], acc[mt][nt], 0, 0, 0);
        }
    };

    if constexpr (PIPE == 0) {
        for (int k0 = 0; k0 < K; k0 += 64) {
            __syncthreads();
            stage(As[0], Bs[0]);
            __syncthreads();
            compute(As[0], Bs[0]);
        }
    } else {
        int nk = K >> 6;
        stage(As[0], Bs[0]);
        stage(As[1], Bs[1]);
        wait_vm<LPS>();
        sbar();
        for (int kt = 0; kt < nk; kt += 2) {
            compute(As[0], Bs[0]);
            sbar();
            if (kt + 2 < nk) { stage(As[0], Bs[0]); wait_vm<LPS>(); }
            else               wait_vm<0>();
            sbar();
            compute(As[1], Bs[1]);
            sbar();
            if (kt + 3 < nk) { stage(As[1], Bs[1]); wait_vm<LPS>(); }
            else               wait_vm<0>();
            sbar();
        }
    }

    size_t cb = (size_t)bz * sC;
    int crow = (lane >> 4) * 4;
    int wrow = wm * 64;
    float psum[4][4];
    float inv[4][4];
    if (EXPSUM) {
        #pragma unroll
        for (int mt = 0; mt < 4; mt++)
            #pragma unroll
            for (int r = 0; r < 4; r++) psum[mt][r] = 0.f;
    }
    if (ROWDIV) {
        #pragma unroll
        for (int mt = 0; mt < 4; mt++)
            #pragma unroll
            for (int r = 0; r < 4; r++) {
                int m = m0 + wrow + mt * 16 + crow + r;
                inv[mt][r] = 1.f / rowsum[(size_t)bz * L_ + m];
            }
    }
    #pragma unroll
    for (int mt = 0; mt < 4; mt++) {
        #pragma unroll
        for (int nt = 0; nt < 4; nt++) {
            int n = n0 + wn * 64 + nt * 16 + fr;
            float bn = 0.f;
            if (BIAS_MODE == 3) bn = (n < 512) ? bias[n] : bias2[n - 512];
            #pragma unroll
            for (int r = 0; r < 4; r++) {
                int m = m0 + wrow + mt * 16 + crow + r;
                float v = acc[mt][nt][r] * alpha;
                if (EXPSUM) { v = __expf(v); psum[mt][r] += v; }
                if (ROWDIV) v *= inv[mt][r];
                if (BIAS_MODE == 3) v += bn;
                if (BIAS_MODE == 2) v += bias[m];
                size_t idx = cb + (size_t)m * ldc + n;
                if (RESID) v += resid[idx];
                if (OUTF32) ((float*)Co)[idx] = v;
                else        ((short*)Co)[idx] = f2b(v);
            }
        }
    }
    if (EXPSUM) {
        #pragma unroll
        for (int mt = 0; mt < 4; mt++)
            #pragma unroll
            for (int r = 0; r < 4; r++) {
                float s = psum[mt][r];
                s += __shfl_xor(s, 1); s += __shfl_xor(s, 2);
                s += __shfl_xor(s, 4); s += __shfl_xor(s, 8);
                if ((lane & 15) == 0) {
                    int m = m0 + wrow + mt * 16 + crow + r;
                    atomicAdd(rowsum + (size_t)bz * L_ + m, s);
                }
            }
    }
}

extern "C" void kernel_launch(void* const* d_in, const int* in_sizes, int n_in,
                              void* d_out, int out_size, void* d_ws, size_t ws_size,
                              hipStream_t stream)
{
    const float* x     = (const float*)d_in[0];
    const float* gamma = (const float*)d_in[1];
    const float* beta  = (const float*)d_in[2];
    const float* Wq    = (const float*)d_in[3];
    const float* bq    = (const float*)d_in[4];
    const float* Wk    = (const float*)d_in[5];
    const float* bk    = (const float*)d_in[6];
    const float* Wv    = (const float*)d_in[7];
    const float* bv    = (const float*)d_in[8];
    const float* Wo    = (const float*)d_in[9];
    const float* bo    = (const float*)d_in[10];
    float* out = (float*)d_out;

    const size_t MiB = 1024 * 1024;
    const size_t CC = (size_t)C_ * C_;
    const size_t LC = (size_t)L_ * C_;
    const size_t LL = (size_t)L_ * L_;
    const size_t wbytes = 4 * CC * sizeof(short);

    const size_t perb = 16 * MiB + L_ * sizeof(float);
    int nb = 1;
    for (int c = 8; c >= 1; c >>= 1)
        if (ws_size >= wbytes + (size_t)c * perb) { nb = c; break; }

    short* wq_b = (short*)d_ws;       // rows 0-511 Wq, 512-1023 Wk (contiguous)
    short* wv_b = wq_b + 2 * CC;
    short* wo_b = wv_b + CC;
    short* h_t  = wo_b + CC;
    short* qk_t = h_t + (size_t)nb * LC;
    short* v_   = qk_t + (size_t)nb * 2 * LC;
    short* S    = v_  + (size_t)nb * LC;
    float* rsum = (float*)(S + (size_t)nb * LL);
    short* a_t  = h_t;                              // h_t dead after vproj

    const long sLC = (long)LC;
    const long sLL = (long)LL;
    const float scale = 0.044194173824159216f;      // 1/sqrt(512)

    cvt_w<<<dim3(C_ * C_ / 1024, 4), 256, 0, stream>>>(Wq, Wk, Wv, Wo, wq_b);

    for (int b0 = 0; b0 < B_; b0 += nb) {
        const float* xb = x + (size_t)b0 * LC;
        float* outb = out + (size_t)b0 * LC;

        groupnorm_tr<<<dim3(nb * G_), 256, 0, stream>>>(xb, gamma, beta, h_t, rsum);

        // qk_t[l, 0..1023] = h_t[l,:]·[Wq;Wk]^T + [bq;bk]   (8-phase 256²)
        gemm8<3><<<dim3(4, 8, nb), 512, 0, stream>>>(
            h_t, wq_b, qk_t, bq, bk, nullptr,
            512, 512, 512, 1024, sLC, 0, 2 * sLC, 1.f);
        // v[c,l] = Wv·h^T + bv   (BM=128 PIPE=1)
        gemm_bt<128, 1, 2, false, false, false, false><<<dim3(16, 4, nb), 256, 0, stream>>>(
            wv_b, h_t, v_, bv, nullptr, nullptr, nullptr,
            2048, 512, 512, 512, 2048, 0, sLC, sLC, 1.f);
        // S = exp(scale * q.k); rowsum partials   (BM=256 PIPE=0, __expf)
        gemm_bt<256, 0, 0, false, false, true, false><<<dim3(16, 8, nb), 512, 0, stream>>>(
            qk_t, qk_t + 512, S, nullptr, nullptr, nullptr, rsum,
            2048, 512, 1024, 1024, 2048, 2 * sLC, 2 * sLC, sLL, scale);
        // a_t[i,c] = (sum_j S[i,j] v[c,j]) / rowsum[i]   (BM=128 PIPE=1)
        gemm_bt<128, 1, 0, false, false, false, true><<<dim3(4, 16, nb), 256, 0, stream>>>(
            S, v_, a_t, nullptr, nullptr, nullptr, rsum,
            512, 2048, 2048, 2048, 512, sLL, sLC, sLC, 1.f);
        // out[c,l] = x[c,l] + bo[c] + Wo·a^T   (fp32 out; BM=128 PIPE=1)
        gemm_bt<128, 1, 2, true, true, false, false><<<dim3(16, 4, nb), 256, 0, stream>>>(
            wo_b, a_t, outb, bo, nullptr, xb, nullptr,
            2048, 512, 512, 512, 2048, 0, sLC, sLC, 1.f);
    }
}